// Round 2
// baseline (154748.657 us; speedup 1.0000x reference)
//
#include <hip/hip_runtime.h>
#include <math.h>

// GRU RNN: T=32768 steps, 2 layers H=512, in=128, out=128, fp32.
// Chunked pipeline (chunk C steps, C adaptive to ws_size):
//   per chunk: igates0 GEMM -> layer-1 scan -> igates1 GEMM -> layer-2 scan
//              -> output GEMM
// Scan = persistent 8-block kernel; W_hh slice in VGPRs, h in LDS, per-step
// h-slice exchange via global memory + release/acquire AGENT-scope flags.

#define TSTEPS 32768
#define HDIM   512
#define G3     1536        // 3*HDIM
#define NBLK   8           // scan blocks
#define SLICE  64          // HDIM / NBLK
#define MAGICF 0x13579BDFu // != 0xAAAAAAAA poison, != 0

// ---------------------------------------------------------------------------
// GEMM: C[M,N] = A[M,K] * B[N,K]^T + bias[N].  BM=128 BN=64 BK=16, 256 thr,
// 8x4 micro-tile per thread. M,N,K all divide the tile sizes for our shapes.
// ---------------------------------------------------------------------------
template<int K>
__global__ __launch_bounds__(256)
void gemm_tn(const float* __restrict__ A, const float* __restrict__ B,
             const float* __restrict__ bias, float* __restrict__ C, int N) {
  __shared__ float As[16][128];
  __shared__ float Bs[16][64];
  const int bm  = blockIdx.x * 128;
  const int bn  = blockIdx.y * 64;
  const int tid = threadIdx.x;
  const int tx  = tid & 15;   // col group: cols bn + tx*4 .. +3
  const int ty  = tid >> 4;   // row group: rows bm + ty*8 .. +7
  const int lr  = tid >> 2;   // staging row 0..63
  const int lk  = tid & 3;    // staging k-chunk 0..3

  float acc[8][4];
#pragma unroll
  for (int i = 0; i < 8; ++i)
#pragma unroll
    for (int jj = 0; jj < 4; ++jj) acc[i][jj] = 0.f;

  for (int k0 = 0; k0 < K; k0 += 16) {
    float4 a0 = *(const float4*)&A[(size_t)(bm + lr) * K + k0 + lk * 4];
    float4 a1 = *(const float4*)&A[(size_t)(bm + lr + 64) * K + k0 + lk * 4];
    float4 bb = *(const float4*)&B[(size_t)(bn + lr) * K + k0 + lk * 4];
    __syncthreads();  // previous iter's readers done before LDS overwrite
    As[lk*4+0][lr]    = a0.x; As[lk*4+1][lr]    = a0.y;
    As[lk*4+2][lr]    = a0.z; As[lk*4+3][lr]    = a0.w;
    As[lk*4+0][lr+64] = a1.x; As[lk*4+1][lr+64] = a1.y;
    As[lk*4+2][lr+64] = a1.z; As[lk*4+3][lr+64] = a1.w;
    Bs[lk*4+0][lr] = bb.x; Bs[lk*4+1][lr] = bb.y;
    Bs[lk*4+2][lr] = bb.z; Bs[lk*4+3][lr] = bb.w;
    __syncthreads();
#pragma unroll
    for (int kk = 0; kk < 16; ++kk) {
      float4 b4  = *(const float4*)&Bs[kk][tx*4];
      float4 av0 = *(const float4*)&As[kk][ty*8];
      float4 av1 = *(const float4*)&As[kk][ty*8+4];
      float av[8] = {av0.x,av0.y,av0.z,av0.w,av1.x,av1.y,av1.z,av1.w};
#pragma unroll
      for (int i = 0; i < 8; ++i) {
        acc[i][0] += av[i]*b4.x; acc[i][1] += av[i]*b4.y;
        acc[i][2] += av[i]*b4.z; acc[i][3] += av[i]*b4.w;
      }
    }
  }
  float4 bv = *(const float4*)&bias[bn + tx*4];
#pragma unroll
  for (int i = 0; i < 8; ++i) {
    float4 o;
    o.x = acc[i][0] + bv.x; o.y = acc[i][1] + bv.y;
    o.z = acc[i][2] + bv.z; o.w = acc[i][3] + bv.w;
    *(float4*)&C[(size_t)(bm + ty*8 + i) * N + bn + tx*4] = o;
  }
}

// ---------------------------------------------------------------------------
// Persistent GRU scan over C local steps. 8 blocks x 512 threads.
// Block b owns h[b*64..b*64+63]. Thread (j=tid>>3, g=tid&7): rows
// {jg, 512+jg, 1024+jg}, k in [g*64, g*64+64). W_hh slice = 48 float4 VGPRs.
// h[t-1] in LDS; rotated chunk order ((i+g)&15) -> 8 k-groups of a wave tile
// all 32 banks, conflict-free ds_read_b128.
// Per step: compute partials -> shfl_xor reduce(8) -> g==0 gates + store
// hout[t] -> __syncthreads (drains vmcnt) -> tid0 RELEASE flag (AGENT:
// buffer_wbl2) -> tids<8 spin ACQUIRE (AGENT: buffer_inv) -> barrier ->
// gather 7 peer slices -> barrier. Blocks stay within one step of each other,
// so reading h_init (= prev chunk's last row, same buffer) at local t=0 is
// safe: row C-1 is only overwritten at local step C-1.
// ---------------------------------------------------------------------------
__global__ __launch_bounds__(512, 2)
void gru_scan(const float* __restrict__ ig,     // [C][1536] input gates (+b)
              const float* __restrict__ Whh,    // [1536][512]
              const float* __restrict__ bnp,    // [512]
              float* __restrict__ hout,         // [C][512]
              const float* __restrict__ h_init, // [512] carry (ignored if first)
              int first,
              unsigned* flags,                  // [C][NBLK], zeroed, step-unique
              int C)
{
  const int b   = blockIdx.x;
  const int tid = threadIdx.x;
  const int j   = tid >> 3;        // 0..63 output index within slice
  const int g   = tid & 7;         // k-group
  const int jg  = b * SLICE + j;   // global h index

  // --- load W_hh slice into registers, in rotated chunk order -------------
  float4 wr[16], wz[16], wn[16];
  {
    const float* Wr = Whh + (size_t)jg            * HDIM + g * 64;
    const float* Wz = Whh + (size_t)(HDIM  + jg)  * HDIM + g * 64;
    const float* Wn = Whh + (size_t)(2*HDIM + jg) * HDIM + g * 64;
#pragma unroll
    for (int i = 0; i < 16; ++i) {
      const int c = (i + g) & 15;
      wr[i] = *(const float4*)(Wr + c * 4);
      wz[i] = *(const float4*)(Wz + c * 4);
      wn[i] = *(const float4*)(Wn + c * 4);
    }
  }
  const float bnj = bnp[jg];

  __shared__ __align__(16) float h_lds[HDIM];
  __shared__ float ig_lds[2][3 * SLICE];

  h_lds[tid] = first ? 0.f : h_init[tid];   // blockDim == HDIM == 512
  const int seg = tid >> 6;                 // ig prefetch: 3 segments of 64
  const int off = tid & 63;
  if (tid < 192)
    ig_lds[0][tid] = ig[(size_t)seg * HDIM + b * SLICE + off];  // local row 0
  __syncthreads();

  const float4* h4 = (const float4*)h_lds;

  for (int t = 0; t < C; ++t) {
    // ---- prefetch igates row t+1 (hides HBM latency under compute) ------
    float pfn = 0.f;
    if (tid < 192 && t + 1 < C)
      pfn = ig[(size_t)(t + 1) * G3 + seg * HDIM + b * SLICE + off];

    // ---- partial dot products over this lane's 64-element k chunk -------
    float4 ar = make_float4(0,0,0,0);
    float4 az = make_float4(0,0,0,0);
    float4 an = make_float4(0,0,0,0);
#pragma unroll
    for (int i = 0; i < 16; ++i) {
      const int c = (i + g) & 15;
      const float4 hv = h4[g * 16 + c];
      ar.x += wr[i].x*hv.x; ar.y += wr[i].y*hv.y; ar.z += wr[i].z*hv.z; ar.w += wr[i].w*hv.w;
      az.x += wz[i].x*hv.x; az.y += wz[i].y*hv.y; az.z += wz[i].z*hv.z; az.w += wz[i].w*hv.w;
      an.x += wn[i].x*hv.x; an.y += wn[i].y*hv.y; an.z += wn[i].z*hv.z; an.w += wn[i].w*hv.w;
    }
    float sr = (ar.x + ar.y) + (ar.z + ar.w);
    float sz = (az.x + az.y) + (az.z + az.w);
    float sn = (an.x + an.y) + (an.z + an.w);
    // reduce across the 8 k-group lanes (lanes j*8..j*8+7, aligned in-wave)
    sr += __shfl_xor(sr, 1); sr += __shfl_xor(sr, 2); sr += __shfl_xor(sr, 4);
    sz += __shfl_xor(sz, 1); sz += __shfl_xor(sz, 2); sz += __shfl_xor(sz, 4);
    sn += __shfl_xor(sn, 1); sn += __shfl_xor(sn, 2); sn += __shfl_xor(sn, 4);

    // ---- gates + state update (one lane per output) ---------------------
    float hnew = 0.f;
    if (g == 0) {
      const float* igc = ig_lds[t & 1];
      const float r = 1.f / (1.f + expf(-(igc[j]           + sr)));
      const float z = 1.f / (1.f + expf(-(igc[SLICE + j]   + sz)));
      const float n = tanhf(igc[2*SLICE + j] + r * (sn + bnj));
      hnew = n + z * (h_lds[jg] - n);
      hout[(size_t)t * HDIM + jg] = hnew;       // publish own slice element
    }
    if (tid < 192 && t + 1 < C) ig_lds[(t + 1) & 1][tid] = pfn;

    __syncthreads();  // drains each wave's vmcnt -> all hout stores in L2

    if (g == 0) h_lds[jg] = hnew;  // own slice local update (no readers now)

    if (tid == 0)
      __hip_atomic_store(&flags[(size_t)t * NBLK + b], MAGICF,
                         __ATOMIC_RELEASE, __HIP_MEMORY_SCOPE_AGENT);
    if (tid < NBLK && tid != b) {
      while (__hip_atomic_load(&flags[(size_t)t * NBLK + tid],
                               __ATOMIC_ACQUIRE, __HIP_MEMORY_SCOPE_AGENT)
             != MAGICF)
        __builtin_amdgcn_s_sleep(2);
    }
    __syncthreads();  // all waves wait until every peer flag observed

    if (tid < HDIM - SLICE) {          // gather the 7 peer slices
      const int m = (tid < b * SLICE) ? tid : tid + SLICE;
      h_lds[m] = hout[(size_t)t * HDIM + m];
    }
    __syncthreads();  // h[t] fully assembled in LDS
  }
}

// ---------------------------------------------------------------------------
extern "C" void kernel_launch(void* const* d_in, const int* in_sizes, int n_in,
                              void* d_out, int out_size, void* d_ws, size_t ws_size,
                              hipStream_t stream) {
  const float* xs    = (const float*)d_in[0];
  const float* W_ih0 = (const float*)d_in[1];
  const float* W_hh0 = (const float*)d_in[2];
  const float* b0    = (const float*)d_in[3];
  const float* bn0   = (const float*)d_in[4];
  const float* W_ih1 = (const float*)d_in[5];
  const float* W_hh1 = (const float*)d_in[6];
  const float* b1    = (const float*)d_in[7];
  const float* bn1   = (const float*)d_in[8];
  const float* W_lin = (const float*)d_in[9];
  const float* b_lin = (const float*)d_in[10];
  float* out = (float*)d_out;

  // Workspace plan: ig[C*1536] + h1c[C*512] + h2c[C*512] + f1[T*8] + f2[T*8].
  const size_t F_BYTES = (size_t)TSTEPS * NBLK * sizeof(unsigned); // 1 MB each
  int C = TSTEPS;
  while (C > 256 && 2 * F_BYTES + (size_t)C * 10240 > ws_size) C >>= 1;
  if (2 * F_BYTES + (size_t)C * 10240 > ws_size) return;  // <5MB ws: give up

  char* ws = (char*)d_ws;
  float*    igb = (float*)(ws);
  float*    h1c = (float*)(ws + (size_t)C * G3 * 4);
  float*    h2c = (float*)(ws + (size_t)C * G3 * 4 + (size_t)C * HDIM * 4);
  unsigned* f1  = (unsigned*)(ws + (size_t)C * 10240);
  unsigned* f2  = (unsigned*)(ws + (size_t)C * 10240 + F_BYTES);

  // Flags must start != MAGICF regardless of ws poison.
  hipMemsetAsync(f1, 0, 2 * F_BYTES, stream);

  const int nchunk = TSTEPS / C;
  for (int c = 0; c < nchunk; ++c) {
    const size_t t0 = (size_t)c * C;
    const int first = (c == 0);
    // igates0 = xs[t0:t0+C] @ W_ih0^T + b0     [C x 1536], K=128
    gemm_tn<128><<<dim3(C/128, G3/64), 256, 0, stream>>>(
        xs + t0 * 128, W_ih0, b0, igb, G3);
    // layer-1 scan chunk -> h1c (carry = h1c last row of previous chunk)
    gru_scan<<<NBLK, 512, 0, stream>>>(
        igb, W_hh0, bn0, h1c, h1c + (size_t)(C - 1) * HDIM, first,
        f1 + t0 * NBLK, C);
    // igates1 = h1c @ W_ih1^T + b1             [C x 1536], K=512
    gemm_tn<512><<<dim3(C/128, G3/64), 256, 0, stream>>>(
        h1c, W_ih1, b1, igb, G3);
    // layer-2 scan chunk -> h2c
    gru_scan<<<NBLK, 512, 0, stream>>>(
        igb, W_hh1, bn1, h2c, h2c + (size_t)(C - 1) * HDIM, first,
        f2 + t0 * NBLK, C);
    // out chunk = h2c @ W_lin^T + b_lin        [C x 128], K=512
    gemm_tn<512><<<dim3(C/128, 128/64), 256, 0, stream>>>(
        h2c, W_lin, b_lin, out + t0 * 128, 128);
  }
}

// Round 3
// 118526.013 us; speedup vs baseline: 1.3056x; 1.3056x over previous
//
#include <hip/hip_runtime.h>
#include <math.h>

// GRU RNN: T=32768 steps, 2 layers H=512, in=128, out=128, fp32.
// Chunked pipeline (chunk C steps, C adaptive to ws_size):
//   per chunk: igates0 GEMM -> layer-1 scan -> igates1 GEMM -> layer-2 scan
//              -> output GEMM
// Scan = persistent 8-block kernel; W_hh slice in VGPRs, h in LDS.
// Inter-block h exchange: fused tagged 64-bit AGENT-scope atomics
// ({tag,value} packed) through a 4-deep global ring -> ONE cross-XCD round
// trip and ONE barrier per step (v1 used flag release/acquire + separate
// gather = 2 round trips + 3 barriers; measured 1.19 us/step best case).

#define TSTEPS 32768
#define HDIM   512
#define G3     1536        // 3*HDIM
#define NBLK   8           // scan blocks
#define SLICE  64          // HDIM / NBLK
#define RING   4           // exchange ring depth (>=2 needed, 4 for margin)

// ---------------------------------------------------------------------------
// GEMM: C[M,N] = A[M,K] * B[N,K]^T + bias[N].  BM=128 BN=64 BK=16, 256 thr,
// 8x4 micro-tile per thread. M,N,K all divide the tile sizes for our shapes.
// ---------------------------------------------------------------------------
template<int K>
__global__ __launch_bounds__(256)
void gemm_tn(const float* __restrict__ A, const float* __restrict__ B,
             const float* __restrict__ bias, float* __restrict__ C, int N) {
  __shared__ float As[16][128];
  __shared__ float Bs[16][64];
  const int bm  = blockIdx.x * 128;
  const int bn  = blockIdx.y * 64;
  const int tid = threadIdx.x;
  const int tx  = tid & 15;   // col group: cols bn + tx*4 .. +3
  const int ty  = tid >> 4;   // row group: rows bm + ty*8 .. +7
  const int lr  = tid >> 2;   // staging row 0..63
  const int lk  = tid & 3;    // staging k-chunk 0..3

  float acc[8][4];
#pragma unroll
  for (int i = 0; i < 8; ++i)
#pragma unroll
    for (int jj = 0; jj < 4; ++jj) acc[i][jj] = 0.f;

  for (int k0 = 0; k0 < K; k0 += 16) {
    float4 a0 = *(const float4*)&A[(size_t)(bm + lr) * K + k0 + lk * 4];
    float4 a1 = *(const float4*)&A[(size_t)(bm + lr + 64) * K + k0 + lk * 4];
    float4 bb = *(const float4*)&B[(size_t)(bn + lr) * K + k0 + lk * 4];
    __syncthreads();  // previous iter's readers done before LDS overwrite
    As[lk*4+0][lr]    = a0.x; As[lk*4+1][lr]    = a0.y;
    As[lk*4+2][lr]    = a0.z; As[lk*4+3][lr]    = a0.w;
    As[lk*4+0][lr+64] = a1.x; As[lk*4+1][lr+64] = a1.y;
    As[lk*4+2][lr+64] = a1.z; As[lk*4+3][lr+64] = a1.w;
    Bs[lk*4+0][lr] = bb.x; Bs[lk*4+1][lr] = bb.y;
    Bs[lk*4+2][lr] = bb.z; Bs[lk*4+3][lr] = bb.w;
    __syncthreads();
#pragma unroll
    for (int kk = 0; kk < 16; ++kk) {
      float4 b4  = *(const float4*)&Bs[kk][tx*4];
      float4 av0 = *(const float4*)&As[kk][ty*8];
      float4 av1 = *(const float4*)&As[kk][ty*8+4];
      float av[8] = {av0.x,av0.y,av0.z,av0.w,av1.x,av1.y,av1.z,av1.w};
#pragma unroll
      for (int i = 0; i < 8; ++i) {
        acc[i][0] += av[i]*b4.x; acc[i][1] += av[i]*b4.y;
        acc[i][2] += av[i]*b4.z; acc[i][3] += av[i]*b4.w;
      }
    }
  }
  float4 bv = *(const float4*)&bias[bn + tx*4];
#pragma unroll
  for (int i = 0; i < 8; ++i) {
    float4 o;
    o.x = acc[i][0] + bv.x; o.y = acc[i][1] + bv.y;
    o.z = acc[i][2] + bv.z; o.w = acc[i][3] + bv.w;
    *(float4*)&C[(size_t)(bm + ty*8 + i) * N + bn + tx*4] = o;
  }
}

// ---------------------------------------------------------------------------
// Persistent GRU scan over C local steps. 8 blocks x 512 threads.
// Block b owns h[b*64..b*64+63]. Thread (j=tid>>3, g=tid&7): rows
// {jg, 512+jg, 1024+jg}, k in [g*64, g*64+64). W_hh slice = 48 float4 VGPRs.
// h[t-1] in double-buffered LDS; rotated chunk order ((i+g)&15) -> the 8
// k-groups of a wave tile all 32 banks, conflict-free ds_read_b128.
// Per step: compute partials from h_lds[p] -> shfl_xor reduce(8) -> g==0
// lanes do gates, store history (plain) + publish {tag,h} via 64-bit RELAXED
// AGENT atomic into ring slot t&3 + write own h_lds[p^1] -> 448 poller
// threads spin on their one peer element's tag (= data arrival, no fence,
// no separate gather) -> ONE __syncthreads -> p^=1.
// Safety: a block at step t implies all peers published t-1, so all data
// <= t-2 is globally consumed -> ring depth 4 >= 2 suffices. Tags are global
// (t0+t+1), never repeat across chunks; ring memset to 0 once per launch.
// ---------------------------------------------------------------------------
__global__ __launch_bounds__(512, 2)
void gru_scan(const float* __restrict__ ig,     // [C][1536] input gates (+b)
              const float* __restrict__ Whh,    // [1536][512]
              const float* __restrict__ bnp,    // [512]
              float* __restrict__ hout,         // [C][512] history (plain)
              const float* __restrict__ h_init, // [512] carry (ignored if first)
              int first,
              unsigned long long* __restrict__ ring, // [RING][512] tagged
              int C, unsigned t0)               // t0 = global step base
{
  const int b   = blockIdx.x;
  const int tid = threadIdx.x;
  const int j   = tid >> 3;        // 0..63 output index within slice
  const int g   = tid & 7;         // k-group
  const int jg  = b * SLICE + j;   // global h index

  // --- load W_hh slice into registers, in rotated chunk order -------------
  float4 wr[16], wz[16], wn[16];
  {
    const float* Wr = Whh + (size_t)jg            * HDIM + g * 64;
    const float* Wz = Whh + (size_t)(HDIM  + jg)  * HDIM + g * 64;
    const float* Wn = Whh + (size_t)(2*HDIM + jg) * HDIM + g * 64;
#pragma unroll
    for (int i = 0; i < 16; ++i) {
      const int c = (i + g) & 15;
      wr[i] = *(const float4*)(Wr + c * 4);
      wz[i] = *(const float4*)(Wz + c * 4);
      wn[i] = *(const float4*)(Wn + c * 4);
    }
  }
  const float bnj = bnp[jg];

  __shared__ __align__(16) float h_lds[2][HDIM];
  __shared__ float ig_lds[2][3 * SLICE];

  h_lds[0][tid] = first ? 0.f : h_init[tid];  // blockDim == HDIM == 512
  const int seg = tid >> 6;                   // ig prefetch: 3 segments of 64
  const int off = tid & 63;
  if (tid < 192)
    ig_lds[0][tid] = ig[(size_t)seg * HDIM + b * SLICE + off];  // local row 0
  // poll mapping: thread m<448 owns peer element pm (skips own slice)
  const int pm = (tid < b * SLICE) ? tid : tid + SLICE;
  __syncthreads();

  int p = 0;
  for (int t = 0; t < C; ++t) {
    // ---- prefetch igates row t+1 (hides HBM latency under compute) ------
    float pfn = 0.f;
    if (tid < 192 && t + 1 < C)
      pfn = ig[(size_t)(t + 1) * G3 + seg * HDIM + b * SLICE + off];

    // ---- partial dot products over this lane's 64-element k chunk -------
    const float4* h4 = (const float4*)h_lds[p];
    float4 ar = make_float4(0,0,0,0);
    float4 az = make_float4(0,0,0,0);
    float4 an = make_float4(0,0,0,0);
#pragma unroll
    for (int i = 0; i < 16; ++i) {
      const int c = (i + g) & 15;
      const float4 hv = h4[g * 16 + c];
      ar.x += wr[i].x*hv.x; ar.y += wr[i].y*hv.y; ar.z += wr[i].z*hv.z; ar.w += wr[i].w*hv.w;
      az.x += wz[i].x*hv.x; az.y += wz[i].y*hv.y; az.z += wz[i].z*hv.z; az.w += wz[i].w*hv.w;
      an.x += wn[i].x*hv.x; an.y += wn[i].y*hv.y; an.z += wn[i].z*hv.z; an.w += wn[i].w*hv.w;
    }
    float sr = (ar.x + ar.y) + (ar.z + ar.w);
    float sz = (az.x + az.y) + (az.z + az.w);
    float sn = (an.x + an.y) + (an.z + an.w);
    // reduce across the 8 k-group lanes (lanes j*8..j*8+7, aligned in-wave)
    sr += __shfl_xor(sr, 1); sr += __shfl_xor(sr, 2); sr += __shfl_xor(sr, 4);
    sz += __shfl_xor(sz, 1); sz += __shfl_xor(sz, 2); sz += __shfl_xor(sz, 4);
    sn += __shfl_xor(sn, 1); sn += __shfl_xor(sn, 2); sn += __shfl_xor(sn, 4);

    const unsigned tag = t0 + (unsigned)t + 1u;
    unsigned long long* slot = ring + (((size_t)(t & (RING - 1))) << 9);

    // ---- gates + state update (one lane per output) ---------------------
    if (g == 0) {
      const float* igc = ig_lds[t & 1];
      const float r = 1.f / (1.f + expf(-(igc[j]           + sr)));
      const float z = 1.f / (1.f + expf(-(igc[SLICE + j]   + sz)));
      const float n = tanhf(igc[2*SLICE + j] + r * (sn + bnj));
      const float hnew = n + z * (h_lds[p][jg] - n);
      hout[(size_t)t * HDIM + jg] = hnew;       // history (plain store)
      const unsigned long long pv =
          ((unsigned long long)tag << 32) | (unsigned)__float_as_uint(hnew);
      __hip_atomic_store(&slot[jg], pv, __ATOMIC_RELAXED,
                         __HIP_MEMORY_SCOPE_AGENT);   // data+flag fused
      h_lds[p ^ 1][jg] = hnew;                  // own slice, next buffer
    }
    if (tid < 192 && t + 1 < C) ig_lds[(t + 1) & 1][tid] = pfn;

    // ---- poll my one peer element (arrival of tag == arrival of data) ---
    if (tid < HDIM - SLICE) {
      unsigned long long vv;
      do {
        vv = __hip_atomic_load(&slot[pm], __ATOMIC_RELAXED,
                               __HIP_MEMORY_SCOPE_AGENT);
      } while ((unsigned)(vv >> 32) != tag);
      h_lds[p ^ 1][pm] = __uint_as_float((unsigned)vv);
    }

    __syncthreads();  // h[t] fully assembled in h_lds[p^1]
    p ^= 1;
  }
}

// ---------------------------------------------------------------------------
extern "C" void kernel_launch(void* const* d_in, const int* in_sizes, int n_in,
                              void* d_out, int out_size, void* d_ws, size_t ws_size,
                              hipStream_t stream) {
  const float* xs    = (const float*)d_in[0];
  const float* W_ih0 = (const float*)d_in[1];
  const float* W_hh0 = (const float*)d_in[2];
  const float* b0    = (const float*)d_in[3];
  const float* bn0   = (const float*)d_in[4];
  const float* W_ih1 = (const float*)d_in[5];
  const float* W_hh1 = (const float*)d_in[6];
  const float* b1    = (const float*)d_in[7];
  const float* bn1   = (const float*)d_in[8];
  const float* W_lin = (const float*)d_in[9];
  const float* b_lin = (const float*)d_in[10];
  float* out = (float*)d_out;

  // Workspace: ig[C*1536] + h1c[C*512] + h2c[C*512] + 2 rings (16KB each).
  const size_t R_BYTES = (size_t)RING * HDIM * sizeof(unsigned long long);
  int C = TSTEPS;
  while (C > 256 && (size_t)C * 10240 + 2 * R_BYTES > ws_size) C >>= 1;
  if ((size_t)C * 10240 + 2 * R_BYTES > ws_size) return;  // tiny ws: give up

  char* ws = (char*)d_ws;
  float* igb = (float*)(ws);
  float* h1c = (float*)(ws + (size_t)C * G3 * 4);
  float* h2c = (float*)(ws + (size_t)C * G3 * 4 + (size_t)C * HDIM * 4);
  unsigned long long* r1 = (unsigned long long*)(ws + (size_t)C * 10240);
  unsigned long long* r2 = (unsigned long long*)(ws + (size_t)C * 10240 + R_BYTES);

  // Rings must start with tags != any t0+t+1 (>=1); ws is poisoned 0xAA.
  hipMemsetAsync(r1, 0, 2 * R_BYTES, stream);

  const int nchunk = TSTEPS / C;
  for (int c = 0; c < nchunk; ++c) {
    const size_t t0 = (size_t)c * C;
    const int first = (c == 0);
    // igates0 = xs[t0:t0+C] @ W_ih0^T + b0     [C x 1536], K=128
    gemm_tn<128><<<dim3(C/128, G3/64), 256, 0, stream>>>(
        xs + t0 * 128, W_ih0, b0, igb, G3);
    // layer-1 scan chunk -> h1c (carry = h1c last row of previous chunk)
    gru_scan<<<NBLK, 512, 0, stream>>>(
        igb, W_hh0, bn0, h1c, h1c + (size_t)(C - 1) * HDIM, first,
        r1, C, (unsigned)t0);
    // igates1 = h1c @ W_ih1^T + b1             [C x 1536], K=512
    gemm_tn<512><<<dim3(C/128, G3/64), 256, 0, stream>>>(
        h1c, W_ih1, b1, igb, G3);
    // layer-2 scan chunk -> h2c
    gru_scan<<<NBLK, 512, 0, stream>>>(
        igb, W_hh1, bn1, h2c, h2c + (size_t)(C - 1) * HDIM, first,
        r2, C, (unsigned)t0);
    // out chunk = h2c @ W_lin^T + b_lin        [C x 128], K=512
    gemm_tn<512><<<dim3(C/128, 128/64), 256, 0, stream>>>(
        h2c, W_lin, b_lin, out + t0 * 128, 128);
  }
}

// Round 4
// 66224.579 us; speedup vs baseline: 2.3367x; 1.7898x over previous
//
#include <hip/hip_runtime.h>
#include <math.h>

// GRU RNN: T=32768, 2 layers H=512, in=128, out=128, fp32.
// v4: BOTH layers fused into one 48-block persistent kernel, pipelined one
// step apart (serial chain halves: 2T -> T steps). The layer-2 input-side
// matvec (W_ih1 @ h1[t], formerly the biggest GEMM) is folded into the
// layer-2 per-step dot over the concatenated 1024-wide input.
//   L1: 16 blocks x 32 rows, k=512  -> 24 float4 weights/thread (VGPR-resident)
//   L2: 32 blocks x 16 rows, k=1024 -> 24 float4 weights/thread
// L1 -> L2 handoff: full-chunk tagged ring (ring1[C][512], tag = global step;
// no wraparound -> L1 may sprint ahead, no deadlock). L2 peer exchange:
// depth-4 tagged ring (lockstep skew <= 1 proven). Tags never collide with
// the 0xAA ws poison; rings memset as insurance.
// Per chunk: ig0 GEMM -> fused scan -> out GEMM.

#define TSTEPS 32768
#define HDIM   512
#define G3     1536
#define NB1    16          // layer-1 blocks
#define NB2    32          // layer-2 blocks
#define S1     32          // rows per L1 block
#define S2     16          // rows per L2 block
#define RING2  4

// ---------------------------------------------------------------------------
// GEMM: C[M,N] = A[M,K] * B[N,K]^T + bias[N].  BM=128 BN=64 BK=16, 256 thr.
// ---------------------------------------------------------------------------
template<int K>
__global__ __launch_bounds__(256)
void gemm_tn(const float* __restrict__ A, const float* __restrict__ B,
             const float* __restrict__ bias, float* __restrict__ C, int N) {
  __shared__ float As[16][128];
  __shared__ float Bs[16][64];
  const int bm  = blockIdx.x * 128;
  const int bn  = blockIdx.y * 64;
  const int tid = threadIdx.x;
  const int tx  = tid & 15;
  const int ty  = tid >> 4;
  const int lr  = tid >> 2;
  const int lk  = tid & 3;

  float acc[8][4];
#pragma unroll
  for (int i = 0; i < 8; ++i)
#pragma unroll
    for (int jj = 0; jj < 4; ++jj) acc[i][jj] = 0.f;

  for (int k0 = 0; k0 < K; k0 += 16) {
    float4 a0 = *(const float4*)&A[(size_t)(bm + lr) * K + k0 + lk * 4];
    float4 a1 = *(const float4*)&A[(size_t)(bm + lr + 64) * K + k0 + lk * 4];
    float4 bb = *(const float4*)&B[(size_t)(bn + lr) * K + k0 + lk * 4];
    __syncthreads();
    As[lk*4+0][lr]    = a0.x; As[lk*4+1][lr]    = a0.y;
    As[lk*4+2][lr]    = a0.z; As[lk*4+3][lr]    = a0.w;
    As[lk*4+0][lr+64] = a1.x; As[lk*4+1][lr+64] = a1.y;
    As[lk*4+2][lr+64] = a1.z; As[lk*4+3][lr+64] = a1.w;
    Bs[lk*4+0][lr] = bb.x; Bs[lk*4+1][lr] = bb.y;
    Bs[lk*4+2][lr] = bb.z; Bs[lk*4+3][lr] = bb.w;
    __syncthreads();
#pragma unroll
    for (int kk = 0; kk < 16; ++kk) {
      float4 b4  = *(const float4*)&Bs[kk][tx*4];
      float4 av0 = *(const float4*)&As[kk][ty*8];
      float4 av1 = *(const float4*)&As[kk][ty*8+4];
      float av[8] = {av0.x,av0.y,av0.z,av0.w,av1.x,av1.y,av1.z,av1.w};
#pragma unroll
      for (int i = 0; i < 8; ++i) {
        acc[i][0] += av[i]*b4.x; acc[i][1] += av[i]*b4.y;
        acc[i][2] += av[i]*b4.z; acc[i][3] += av[i]*b4.w;
      }
    }
  }
  float4 bv = *(const float4*)&bias[bn + tx*4];
#pragma unroll
  for (int i = 0; i < 8; ++i) {
    float4 o;
    o.x = acc[i][0] + bv.x; o.y = acc[i][1] + bv.y;
    o.z = acc[i][2] + bv.z; o.w = acc[i][3] + bv.w;
    *(float4*)&C[(size_t)(bm + ty*8 + i) * N + bn + tx*4] = o;
  }
}

// ---------------------------------------------------------------------------
// Fused 2-layer pipelined scan. Grid = NB1 + NB2 = 48 blocks x 512 threads.
// ---------------------------------------------------------------------------
__global__ __launch_bounds__(512, 2)
void gru2_scan(const float* __restrict__ ig0,   // [C][1536] layer-1 igates
               const float* __restrict__ Whh0,  // [1536][512]
               const float* __restrict__ bn0,   // [512]
               const float* __restrict__ Wih1,  // [1536][512]
               const float* __restrict__ Whh1,  // [1536][512]
               const float* __restrict__ b1v,   // [1536]
               const float* __restrict__ bn1,   // [512]
               float* __restrict__ h1carry,     // [512] cross-chunk carry
               float* __restrict__ h2c,         // [C][512] layer-2 history
               unsigned long long* __restrict__ ring1, // [C][512]
               unsigned long long* __restrict__ ring2, // [RING2][512]
               int C, unsigned t0, int first)
{
  const int tid = threadIdx.x;
  __shared__ __align__(16) float u[2][1024];   // L1 uses [.][0..511]
  __shared__ float igl[2][96];

  if (blockIdx.x < NB1) {
    // =================== layer 1 ===================
    const int b  = blockIdx.x;
    const int j  = tid >> 4;        // 0..31 row in slice
    const int g  = tid & 15;        // k-group (32 floats)
    const int jg = b * S1 + j;
    float4 wr[8], wz[8], wn[8];
    {
      const float* Wr = Whh0 + (size_t)jg            * HDIM + g * 32;
      const float* Wz = Whh0 + (size_t)(HDIM  + jg)  * HDIM + g * 32;
      const float* Wn = Whh0 + (size_t)(2*HDIM + jg) * HDIM + g * 32;
#pragma unroll
      for (int i = 0; i < 8; ++i) {
        const int c = (i + g) & 7;            // rotation: 2-way banks (free)
        wr[i] = *(const float4*)(Wr + c * 4);
        wz[i] = *(const float4*)(Wz + c * 4);
        wn[i] = *(const float4*)(Wn + c * 4);
      }
    }
    const float bnj = bn0[jg];
    u[0][tid] = first ? 0.f : h1carry[tid];
    if (tid < 96)
      igl[0][tid] = ig0[(size_t)(tid >> 5) * HDIM + b * S1 + (tid & 31)];
    const int pm = (tid < b * S1) ? tid : tid + S1;   // 480 pollers
    __syncthreads();

    int p = 0;
    for (int t = 0; t < C; ++t) {
      float pfn = 0.f;
      if (tid < 96 && t + 1 < C)
        pfn = ig0[(size_t)(t + 1) * G3 + (size_t)(tid >> 5) * HDIM
                  + b * S1 + (tid & 31)];

      const float4* h4 = (const float4*)u[p];
      float4 ar = make_float4(0,0,0,0), az = make_float4(0,0,0,0),
             an = make_float4(0,0,0,0);
#pragma unroll
      for (int i = 0; i < 8; ++i) {
        const int c = (i + g) & 7;
        const float4 hv = h4[g * 8 + c];
        ar.x += wr[i].x*hv.x; ar.y += wr[i].y*hv.y; ar.z += wr[i].z*hv.z; ar.w += wr[i].w*hv.w;
        az.x += wz[i].x*hv.x; az.y += wz[i].y*hv.y; az.z += wz[i].z*hv.z; az.w += wz[i].w*hv.w;
        an.x += wn[i].x*hv.x; an.y += wn[i].y*hv.y; an.z += wn[i].z*hv.z; an.w += wn[i].w*hv.w;
      }
      float sr = (ar.x + ar.y) + (ar.z + ar.w);
      float sz = (az.x + az.y) + (az.z + az.w);
      float sn = (an.x + an.y) + (an.z + an.w);
      sr += __shfl_xor(sr,1); sr += __shfl_xor(sr,2); sr += __shfl_xor(sr,4); sr += __shfl_xor(sr,8);
      sz += __shfl_xor(sz,1); sz += __shfl_xor(sz,2); sz += __shfl_xor(sz,4); sz += __shfl_xor(sz,8);
      sn += __shfl_xor(sn,1); sn += __shfl_xor(sn,2); sn += __shfl_xor(sn,4); sn += __shfl_xor(sn,8);

      const unsigned tag = t0 + (unsigned)t + 1u;
      if (g == 0) {
        const float* igc = igl[t & 1];
        const float r = 1.f / (1.f + expf(-(igc[j]      + sr)));
        const float z = 1.f / (1.f + expf(-(igc[32 + j] + sz)));
        const float n = tanhf(igc[64 + j] + r * (sn + bnj));
        const float hnew = n + z * (u[p][jg] - n);
        __hip_atomic_store(&ring1[(size_t)t * HDIM + jg],
            ((unsigned long long)tag << 32) | (unsigned)__float_as_uint(hnew),
            __ATOMIC_RELAXED, __HIP_MEMORY_SCOPE_AGENT);
        u[p ^ 1][jg] = hnew;
        if (t == C - 1) h1carry[jg] = hnew;
      }
      if (tid < 96 && t + 1 < C) igl[(t + 1) & 1][tid] = pfn;

      if (tid < HDIM - S1) {                    // gather peers' h1[t]
        unsigned long long vv;
        do {
          vv = __hip_atomic_load(&ring1[(size_t)t * HDIM + pm],
                                 __ATOMIC_RELAXED, __HIP_MEMORY_SCOPE_AGENT);
        } while ((unsigned)(vv >> 32) != tag);
        u[p ^ 1][pm] = __uint_as_float((unsigned)vv);
      }
      __syncthreads();
      p ^= 1;
    }
  } else {
    // =================== layer 2 ===================
    const int b  = blockIdx.x - NB1;
    const int j  = tid >> 5;        // 0..15 row in slice
    const int g  = tid & 31;        // k-group (32 of 1024 floats)
    const int jg = b * S2 + j;
    float4 wr[8], wz[8], wn[8];
    {
      const float* base = (g < 16) ? Wih1 : Whh1;   // concat [h1 || h2] k-split
      const int gk = (g & 15) * 32;
      const float* Wr = base + (size_t)jg            * HDIM + gk;
      const float* Wz = base + (size_t)(HDIM  + jg)  * HDIM + gk;
      const float* Wn = base + (size_t)(2*HDIM + jg) * HDIM + gk;
#pragma unroll
      for (int i = 0; i < 8; ++i) {
        const int c = (i + g) & 7;
        wr[i] = *(const float4*)(Wr + c * 4);
        wz[i] = *(const float4*)(Wz + c * 4);
        wn[i] = *(const float4*)(Wn + c * 4);
      }
    }
    const float b1r = b1v[jg], b1z = b1v[HDIM + jg], b1n = b1v[2*HDIM + jg];
    const float bnj = bn1[jg];

    // init: u[0] = [h1[0] (poll) || h2 carry]
    u[0][512 + tid] = first ? 0.f : h2c[(size_t)(C - 1) * HDIM + tid];
    {
      unsigned long long vv;
      do {
        vv = __hip_atomic_load(&ring1[tid], __ATOMIC_RELAXED,
                               __HIP_MEMORY_SCOPE_AGENT);
      } while ((unsigned)(vv >> 32) != t0 + 1u);
      u[0][tid] = __uint_as_float((unsigned)vv);
    }
    const int pm2 = (tid < b * S2) ? tid : tid + S2;  // 496 pollers
    __syncthreads();

    int p = 0;
    for (int t = 0; t < C; ++t) {
      const float4* u4 = (const float4*)u[p];
      float4 ar = make_float4(0,0,0,0), az = make_float4(0,0,0,0),
             an = make_float4(0,0,0,0);
#pragma unroll
      for (int i = 0; i < 8; ++i) {
        const int c = (i + g) & 7;
        const float4 hv = u4[g * 8 + c];
        ar.x += wr[i].x*hv.x; ar.y += wr[i].y*hv.y; ar.z += wr[i].z*hv.z; ar.w += wr[i].w*hv.w;
        az.x += wz[i].x*hv.x; az.y += wz[i].y*hv.y; az.z += wz[i].z*hv.z; az.w += wz[i].w*hv.w;
        an.x += wn[i].x*hv.x; an.y += wn[i].y*hv.y; an.z += wn[i].z*hv.z; an.w += wn[i].w*hv.w;
      }
      float sr = (ar.x + ar.y) + (ar.z + ar.w);
      float sz = (az.x + az.y) + (az.z + az.w);
      float sn = (an.x + an.y) + (an.z + an.w);
      // r,z: full 32-lane sum. n: keep ih half (g<16) and hh half separate.
      sr += __shfl_xor(sr,1); sr += __shfl_xor(sr,2); sr += __shfl_xor(sr,4); sr += __shfl_xor(sr,8);
      sz += __shfl_xor(sz,1); sz += __shfl_xor(sz,2); sz += __shfl_xor(sz,4); sz += __shfl_xor(sz,8);
      sn += __shfl_xor(sn,1); sn += __shfl_xor(sn,2); sn += __shfl_xor(sn,4); sn += __shfl_xor(sn,8);
      sr += __shfl_xor(sr, 16);
      sz += __shfl_xor(sz, 16);
      const float snb = __shfl_xor(sn, 16);   // at g==0: hh-half sum

      const unsigned tag = t0 + (unsigned)t + 1u;
      if (g == 0) {
        const float r = 1.f / (1.f + expf(-(sr + b1r)));
        const float z = 1.f / (1.f + expf(-(sz + b1z)));
        const float n = tanhf((sn + b1n) + r * (snb + bnj));
        const float hnew = n + z * (u[p][512 + jg] - n);
        h2c[(size_t)t * HDIM + jg] = hnew;
        __hip_atomic_store(&ring2[(size_t)((t & (RING2-1)) << 9) + jg],
            ((unsigned long long)tag << 32) | (unsigned)__float_as_uint(hnew),
            __ATOMIC_RELAXED, __HIP_MEMORY_SCOPE_AGENT);
        u[p ^ 1][512 + jg] = hnew;
      }

      if (t + 1 < C) {                 // h1[t+1] from L1 (usually already there)
        unsigned long long vv;
        do {
          vv = __hip_atomic_load(&ring1[(size_t)(t + 1) * HDIM + tid],
                                 __ATOMIC_RELAXED, __HIP_MEMORY_SCOPE_AGENT);
        } while ((unsigned)(vv >> 32) != tag + 1u);
        u[p ^ 1][tid] = __uint_as_float((unsigned)vv);
      }
      if (tid < HDIM - S2) {           // peers' h2[t]
        unsigned long long vv;
        do {
          vv = __hip_atomic_load(&ring2[(size_t)((t & (RING2-1)) << 9) + pm2],
                                 __ATOMIC_RELAXED, __HIP_MEMORY_SCOPE_AGENT);
        } while ((unsigned)(vv >> 32) != tag);
        u[p ^ 1][512 + pm2] = __uint_as_float((unsigned)vv);
      }
      __syncthreads();
      p ^= 1;
    }
  }
}

// ---------------------------------------------------------------------------
extern "C" void kernel_launch(void* const* d_in, const int* in_sizes, int n_in,
                              void* d_out, int out_size, void* d_ws, size_t ws_size,
                              hipStream_t stream) {
  const float* xs    = (const float*)d_in[0];
  const float* W_ih0 = (const float*)d_in[1];
  const float* W_hh0 = (const float*)d_in[2];
  const float* b0    = (const float*)d_in[3];
  const float* bn0   = (const float*)d_in[4];
  const float* W_ih1 = (const float*)d_in[5];
  const float* W_hh1 = (const float*)d_in[6];
  const float* b1    = (const float*)d_in[7];
  const float* bn1   = (const float*)d_in[8];
  const float* W_lin = (const float*)d_in[9];
  const float* b_lin = (const float*)d_in[10];
  float* out = (float*)d_out;

  // ws layout per chunk of C steps:
  //   ig0[C*1536] f32 | h2c[C*512] f32 | ring1[C*512] u64 | ring2[4*512] u64
  //   | h1carry[512] f32
  const size_t TAIL = (size_t)RING2 * HDIM * 8 + HDIM * 4;   // 18 KB
  int C = TSTEPS;
  while (C > 256 && (size_t)C * 12288 + TAIL > ws_size) C >>= 1;
  if ((size_t)C * 12288 + TAIL > ws_size) return;

  char* ws = (char*)d_ws;
  float*              igb = (float*)(ws);
  float*              h2c = (float*)(ws + (size_t)C * 6144);
  unsigned long long* r1  = (unsigned long long*)(ws + (size_t)C * 8192);
  unsigned long long* r2  = (unsigned long long*)(ws + (size_t)C * 12288);
  float*              h1c = (float*)(ws + (size_t)C * 12288 + RING2 * HDIM * 8);

  // Insurance: tags must start != any t0+t+1 (0xAA poison already can't match).
  hipMemsetAsync(r1, 0, (size_t)C * HDIM * 8 + RING2 * HDIM * 8, stream);

  const int nchunk = TSTEPS / C;
  for (int c = 0; c < nchunk; ++c) {
    const size_t t0 = (size_t)c * C;
    const int first = (c == 0);
    // igates0 = xs[t0:t0+C] @ W_ih0^T + b0     [C x 1536], K=128
    gemm_tn<128><<<dim3(C/128, G3/64), 256, 0, stream>>>(
        xs + t0 * 128, W_ih0, b0, igb, G3);
    // fused pipelined 2-layer scan chunk -> h2c
    gru2_scan<<<NB1 + NB2, 512, 0, stream>>>(
        igb, W_hh0, bn0, W_ih1, W_hh1, b1, bn1, h1c, h2c,
        r1, r2, C, (unsigned)t0, first);
    // out chunk = h2c @ W_lin^T + b_lin        [C x 128], K=512
    gemm_tn<512><<<dim3(C/128, 128/64), 256, 0, stream>>>(
        h2c, W_lin, b_lin, out + t0 * 128, 128);
  }
}